// Round 12
// baseline (122.269 us; speedup 1.0000x reference)
//
#include <hip/hip_runtime.h>

// ---------------------------------------------------------------------------
// Per-batch dynamic conv stack + polynomial attention (f32).
//   feature (8,360) = mean(thumb,(2,3)) @ Wm + bm
//   conv_stack: residual + [3x conv3x3(SAME,leaky 0.2)] -> [5x conv1x1(leaky)]
//   attention:  out = y * (1 + prod_i(a*h + b*w + c*y + d)) per channel
// Outputs: x_out (8,3,512,512) then thumb_out (8,3,64,64), flat f32.
//
// R19 = R18 discipline (pk-f32, col-major in-place LDS, T14 stage0, 256 thr)
// on 16x128 tiles with NC=8 conv units:
//   * R17/R18 killed the occupancy lever (bigger blocks hurt, smaller LDS
//     null) -> TLP pinned ~2.4 waves/SIMD. Remaining lever: ILP per wave.
//   * NC=8: 20 pair-loads per 8 cols (2.5/col vs 3/col at NC=4) -> -17%
//     LDS issue; 20 independent ds_read2 in flight per ich vs 12.
//   * 128-wide tile: 1056 blocks, barriers/stage-overheads per pixel
//     halved; halo amp 136/128. conv1 170 units, conv2 153 (one round);
//     conv3+epilogue NC=2 x 2 rounds on all 256 threads.
//   * Same halo-4 semantics as R9..R18 (conv1 valid -3..130 -> conv2 valid
//     -1..128 -> conv3 exact 0..127). Thumb (W=64): guards zero-load cols
//     >=64, store guard drops them.
//   * LDS 37.8KB (4 blocks/CU), __launch_bounds__(256,3) for NC=8 regs
//     (~130 live; cap ~170, no spill — R6 rule).
// ---------------------------------------------------------------------------

typedef float v2f __attribute__((ext_vector_type(2)));
#define FMA2(a, b, c) __builtin_elementwise_fma((a), (b), (c))

__device__ __forceinline__ v2f leaky2(v2f v) {
    return __builtin_elementwise_max(v, v * 0.2f);
}

// align-4 LDS pair load/store: compiles to ds_read2_b32 / ds_write2_b32
__device__ __forceinline__ v2f ldpair(const float* p) {
    v2f r; __builtin_memcpy(&r, p, 8); return r;
}
__device__ __forceinline__ void stpair(float* p, v2f v) {
    __builtin_memcpy(p, &v, 8);
}

constexpr int NCOLS = 137;          // cols -4..131 + zero pad col 136
constexpr int CSTR  = 23;           // 22 rows + 1 pad; 4*23=92=28 mod 32 banks
constexpr int CHS   = NCOLS * CSTR; // 3151
constexpr int BUFSZ = 3 * CHS + 4;  // 37.8KB

__global__ __launch_bounds__(384) void prep_kernel(
    const float* __restrict__ thumb, const float* __restrict__ Wm,
    const float* __restrict__ bm, float* __restrict__ feat)
{
    const int b = blockIdx.x;                // 8 blocks
    const int t = threadIdx.x;               // 384
    const int ch = t >> 7;                   // 0..2
    const int l  = t & 127;
    const float4* p = (const float4*)(thumb + (size_t)b * 3 * 4096);
    float s = 0.f;
#pragma unroll
    for (int k = 0; k < 8; ++k) {
        float4 v = p[ch * 1024 + l + k * 128];
        s += v.x + v.y + v.z + v.w;
    }
    __shared__ float red[384];
    red[t] = s;
    __syncthreads();
    for (int off = 64; off > 0; off >>= 1) {
        if (l < off) red[t] += red[t + off];
        __syncthreads();
    }
    if (t < 360) {
        const float sc = 1.f / 4096.f;
        const float m0 = red[0] * sc, m1 = red[128] * sc, m2 = red[256] * sc;
        feat[b * 360 + t] =
            fmaf(m0, Wm[t], fmaf(m1, Wm[360 + t], fmaf(m2, Wm[720 + t], bm[t])));
    }
}

// Packed 3x3 conv over a strip of 2 output rows x NC cols, all 3 och.
// acc[oc][c] = (row r0, row r0+1) packed. rb = buffer row of the first tap
// pair (taps cover buffer rows rb..rb+3). Per (ich, window col) load the
// two disjoint pairs p0=(rb,rb+1), p1=(rb+2,rb+3); middle pm={p0.y,p1.x}.
// gx may be -4 (halo): window col 0 clamps to col 3, feeding only
// discarded outputs.
template<int NC>
__device__ __forceinline__ void conv_rows_pk(
    const float* __restrict__ buf, const float* __restrict__ fw,
    int rb, int gx, v2f acc[3][NC])
{
    const float b0 = fw[81], b1 = fw[82], b2 = fw[83];
#pragma unroll
    for (int c = 0; c < NC; ++c) {
        v2f i0 = {b0, b0}; v2f i1 = {b1, b1}; v2f i2 = {b2, b2};
        acc[0][c] = i0; acc[1][c] = i1; acc[2][c] = i2;
    }
    const int c0 = (gx < 0) ? 3 : gx + 3;
#pragma unroll
    for (int ich = 0; ich < 3; ++ich) {
        const int base = ich * CHS + rb;
        v2f p0[NC + 2], p1[NC + 2], pm[NC + 2];
#pragma unroll
        for (int k = 0; k < NC + 2; ++k) {
            const int cc = (k == 0) ? c0 : (gx + 3 + k);
            p0[k] = ldpair(&buf[base + cc * CSTR]);
            p1[k] = ldpair(&buf[base + cc * CSTR + 2]);
            v2f m = {p0[k].y, p1[k].x};
            pm[k] = m;
        }
#pragma unroll
        for (int dy = 0; dy < 3; ++dy) {
#pragma unroll
            for (int oc = 0; oc < 3; ++oc) {
                const float w0 = fw[oc * 27 + ich * 9 + dy * 3 + 0];
                const float w1 = fw[oc * 27 + ich * 9 + dy * 3 + 1];
                const float w2 = fw[oc * 27 + ich * 9 + dy * 3 + 2];
                v2f W0 = {w0, w0}; v2f W1 = {w1, w1}; v2f W2 = {w2, w2};
#pragma unroll
                for (int c = 0; c < NC; ++c) {
                    const v2f wa = (dy == 0) ? p0[c]     : (dy == 1) ? pm[c]     : p1[c];
                    const v2f wb = (dy == 0) ? p0[c + 1] : (dy == 1) ? pm[c + 1] : p1[c + 1];
                    const v2f wc = (dy == 0) ? p0[c + 2] : (dy == 1) ? pm[c + 2] : p1[c + 2];
                    acc[oc][c] = FMA2(wa, W0, FMA2(wb, W1, FMA2(wc, W2, acc[oc][c])));
                }
            }
        }
    }
}

__global__ __launch_bounds__(256, 3) void conv_att_kernel(
    const float* __restrict__ x, const float* __restrict__ thumb,
    const float* __restrict__ feat, float* __restrict__ out)
{
    __shared__ float buf[BUFSZ];

    int id = blockIdx.x;
    const float* src; float* dst; int H, W, b, trow, tcol;
    if (id < 1024) {                 // big: 8 batches x (32 bands x 4 cols)
        b = id >> 7; const int t = id & 127;
        H = 512; W = 512; trow = (t >> 2) * 16; tcol = (t & 3) * 128;
        src = x; dst = out;
    } else {                         // thumb: 8 batches x 4 row tiles (W=64)
        const int i2 = id - 1024;
        b = i2 >> 2; trow = (i2 & 3) * 16; tcol = 0;
        H = 64; W = 64; src = thumb;
        dst = out + (size_t)8 * 3 * 512 * 512;
    }
    const float* fb = feat + b * 360;    // uniform -> scalar loads
    const int tid = threadIdx.x;

    // ---- stage0: issue ALL global loads first (regs), then write LDS ----
    // interior: 3ch x 22 rows x 32 quads = 2112 units; 8 full rounds + 64.
    const float* sbg = src + (size_t)b * 3 * H * W;
    float4 stv[8];
#pragma unroll
    for (int i = 0; i < 8; ++i) {
        const int q = tid + 256 * i;           // < 2048
        const int c = q / 704;                 // 704 = 22*32
        const int rem = q - c * 704;
        const int mr = rem >> 5;
        const int k  = rem & 31;
        const int gr = trow + mr - 3;
        const int gc0 = tcol + 4 * k;
        float4 v = make_float4(0.f, 0.f, 0.f, 0.f);
        if ((unsigned)gr < (unsigned)H && (unsigned)gc0 <= (unsigned)(W - 4))
            v = *(const float4*)&sbg[(size_t)c * H * W + (size_t)gr * W + gc0];
        stv[i] = v;
    }
    const bool has9 = tid < 64;                // q = 2048..2111 (c = 2)
    float4 st9 = make_float4(0.f, 0.f, 0.f, 0.f);
    if (has9) {
        const int rem = 640 + tid;             // c = 2
        const int mr = rem >> 5;
        const int k  = rem & 31;
        const int gr = trow + mr - 3;
        const int gc0 = tcol + 4 * k;
        if ((unsigned)gr < (unsigned)H && (unsigned)gc0 <= (unsigned)(W - 4))
            st9 = *(const float4*)&sbg[(size_t)2 * H * W + (size_t)gr * W + gc0];
    }
    // halo: cols 0..3 (img tcol-4) and 132..135 (img tcol+128), 132 units
    const bool hasH = tid < 132;
    float4 hv = make_float4(0.f, 0.f, 0.f, 0.f);
    int hc = 0, hmr = 0, hside = 0;
    if (hasH) {
        hc = tid / 44;                         // 44 = 22*2
        const int rem = tid - hc * 44;
        hmr = rem >> 1;
        hside = rem & 1;
        const int gr = trow + hmr - 3;
        const int gc0 = tcol + (hside ? 128 : -4);
        const bool rok = (unsigned)gr < (unsigned)H;
        const float* gp = sbg + (size_t)hc * H * W + (size_t)(rok ? gr : 0) * W;
        if (rok && (unsigned)gc0 <= (unsigned)(W - 4)) {
            hv = *(const float4*)&gp[gc0];
        } else {
            hv.x = (rok && (unsigned)(gc0 + 0) < (unsigned)W) ? gp[gc0 + 0] : 0.f;
            hv.y = (rok && (unsigned)(gc0 + 1) < (unsigned)W) ? gp[gc0 + 1] : 0.f;
            hv.z = (rok && (unsigned)(gc0 + 2) < (unsigned)W) ? gp[gc0 + 2] : 0.f;
            hv.w = (rok && (unsigned)(gc0 + 3) < (unsigned)W) ? gp[gc0 + 3] : 0.f;
        }
    }
    // writes (transpose into col-major buffer; buffer col = img col + 4,
    // buffer row = img row + 3)
#pragma unroll
    for (int i = 0; i < 8; ++i) {
        const int q = tid + 256 * i;
        const int c = q / 704;
        const int rem = q - c * 704;
        const int mr = rem >> 5;
        const int k  = rem & 31;
        float* bp = &buf[c * CHS + (4 * k + 4) * CSTR + mr];
        bp[0] = stv[i].x; bp[CSTR] = stv[i].y;
        bp[2 * CSTR] = stv[i].z; bp[3 * CSTR] = stv[i].w;
    }
    if (has9) {
        const int rem = 640 + tid;
        const int mr = rem >> 5;
        const int k  = rem & 31;
        float* bp = &buf[2 * CHS + (4 * k + 4) * CSTR + mr];
        bp[0] = st9.x; bp[CSTR] = st9.y; bp[2 * CSTR] = st9.z; bp[3 * CSTR] = st9.w;
    }
    if (hasH) {
        float* bp = &buf[hc * CHS + (hside ? 132 : 0) * CSTR + hmr];
        bp[0] = hv.x; bp[CSTR] = hv.y; bp[2 * CSTR] = hv.z; bp[3 * CSTR] = hv.w;
    }
    // zero pad col 136 (rows 0..21): only right-edge windows read it,
    // feeding discarded outputs — keep values defined. Never overwritten.
    if (tid < 66) {
        const int c = tid / 22, mr = tid - c * 22;
        buf[c * CHS + 136 * CSTR + mr] = 0.f;
    }
    __syncthreads();

    // ---- phase 2: conv1 reads + residual stash (all reads before writes)
    // conv1: 10 strips (r0 = 2s-2) x 17 groups of 8 cols = 170 units.
    const bool act1 = tid < 170;
    int s1 = 0, gx1 = 0;
    if (act1) { s1 = tid / 17; gx1 = 8 * (tid - s1 * 17) - 4; }
    v2f acc[3][8];
    if (act1) conv_rows_pk<8>(buf, fb, 2 * s1, gx1, acc);   // rb = r0+2 = 2s

    // epilogue mapping: 2 rounds of (strip s3e = u>>6 rows (2s3e,2s3e+1),
    // cols gx3e = 2*(u&63)); residual from input buffer rows 2s3e+3.
    v2f res2[2][3][2];
#pragma unroll
    for (int r = 0; r < 2; ++r) {
        const int u = tid + 256 * r;
        const int s3e = u >> 6;
        const int gx3e = 2 * (u & 63);
#pragma unroll
        for (int ch = 0; ch < 3; ++ch)
#pragma unroll
            for (int c = 0; c < 2; ++c)
                res2[r][ch][c] = ldpair(&buf[ch * CHS + (gx3e + 4 + c) * CSTR + (2 * s3e + 3)]);
    }
    __syncthreads();

    // conv1 writes: buffer rows 2s1+1, 2s1+2 (img rows r0, r0+1)
    if (act1) {
#pragma unroll
        for (int oc = 0; oc < 3; ++oc)
#pragma unroll
            for (int c = 0; c < 8; ++c)
                stpair(&buf[oc * CHS + (gx1 + 4 + c) * CSTR + (2 * s1 + 1)],
                       leaky2(acc[oc][c]));
    }
    __syncthreads();

    // ---- phase 3: conv2 (in-place): 9 strips (r0 = 2s-1) x 17 = 153 units
    const bool act2 = tid < 153;
    int s2 = 0, gx2 = 0;
    if (act2) { s2 = tid / 17; gx2 = 8 * (tid - s2 * 17) - 4; }
    if (act2) conv_rows_pk<8>(buf, fb + 84, 2 * s2 + 1, gx2, acc); // rb = r0+2
    __syncthreads();

    // conv2 writes: buffer rows 2s2+2, 2s2+3 (img rows r0, r0+1)
    if (act2) {
#pragma unroll
        for (int oc = 0; oc < 3; ++oc)
#pragma unroll
            for (int c = 0; c < 8; ++c)
                stpair(&buf[oc * CHS + (gx2 + 4 + c) * CSTR + (2 * s2 + 2)],
                       leaky2(acc[oc][c]));
    }
    __syncthreads();

    // ---- phase 4: conv3 (NC=2, 2 rounds, ALL 256 threads) + 1x1 chain
    //      + residual + attention + 8B stores ----
    const float invH = 1.f / (float)H;
    const float invW = 1.f / (float)W;
#pragma unroll
    for (int r = 0; r < 2; ++r) {
        const int u = tid + 256 * r;
        const int s3e = u >> 6;              // strip 0..7
        const int gx3e = 2 * (u & 63);       // 0..126
        v2f y[3][2];
        {
            v2f acc3[3][2];
            conv_rows_pk<2>(buf, fb + 168, 2 * s3e + 2, gx3e, acc3); // rb = r0+2
#pragma unroll
            for (int oc = 0; oc < 3; ++oc)
#pragma unroll
                for (int c = 0; c < 2; ++c) y[oc][c] = leaky2(acc3[oc][c]);
        }

        // 5x conv1x1 chain, packed over the row pair
#pragma unroll
        for (int lay = 0; lay < 5; ++lay) {
            const float* fw = fb + 252 + lay * 12;
            v2f W0 = {fw[0], fw[0]}; v2f W1 = {fw[1], fw[1]}; v2f W2 = {fw[2], fw[2]};
            v2f W3 = {fw[3], fw[3]}; v2f W4 = {fw[4], fw[4]}; v2f W5 = {fw[5], fw[5]};
            v2f W6 = {fw[6], fw[6]}; v2f W7 = {fw[7], fw[7]}; v2f W8 = {fw[8], fw[8]};
            v2f C0 = {fw[9], fw[9]}; v2f C1 = {fw[10], fw[10]}; v2f C2 = {fw[11], fw[11]};
            v2f z0[2], z1[2], z2[2];
#pragma unroll
            for (int c = 0; c < 2; ++c) {
                z0[c] = FMA2(y[0][c], W0, FMA2(y[1][c], W1, FMA2(y[2][c], W2, C0)));
                z1[c] = FMA2(y[0][c], W3, FMA2(y[1][c], W4, FMA2(y[2][c], W5, C1)));
                z2[c] = FMA2(y[0][c], W6, FMA2(y[1][c], W7, FMA2(y[2][c], W8, C2)));
            }
#pragma unroll
            for (int c = 0; c < 2; ++c) {
                y[0][c] = leaky2(z0[c]);
                y[1][c] = leaky2(z1[c]);
                y[2][c] = leaky2(z2[c]);
            }
        }

        // residual + attention + store (2 rows x 2 cols x 3 ch)
        const int gr0 = trow + 2 * s3e;
        const bool stok = (tcol + gx3e) <= (W - 2);   // thumb: drop cols >= W
        if (stok) {
            v2f h2 = {(float)gr0 * invH, (float)(gr0 + 1) * invH};
            const float wb = (float)(tcol + gx3e) * invW;
            const v2f one = {1.f, 1.f};
#pragma unroll
            for (int ch = 0; ch < 3; ++ch) {
                const float* fp = fb + 312 + ch * 16;
                v2f PA0 = {fp[0], fp[0]},  PB0 = {fp[1], fp[1]},  PC0 = {fp[2], fp[2]},  PD0 = {fp[3], fp[3]};
                v2f PA1 = {fp[4], fp[4]},  PB1 = {fp[5], fp[5]},  PC1 = {fp[6], fp[6]},  PD1 = {fp[7], fp[7]};
                v2f PA2 = {fp[8], fp[8]},  PB2 = {fp[9], fp[9]},  PC2 = {fp[10], fp[10]}, PD2 = {fp[11], fp[11]};
                v2f PA3 = {fp[12], fp[12]}, PB3 = {fp[13], fp[13]}, PC3 = {fp[14], fp[14]}, PD3 = {fp[15], fp[15]};
                v2f t0 = FMA2(PA0, h2, PD0);
                v2f t1 = FMA2(PA1, h2, PD1);
                v2f t2 = FMA2(PA2, h2, PD2);
                v2f t3 = FMA2(PA3, h2, PD3);
                v2f o[2];
#pragma unroll
                for (int c = 0; c < 2; ++c) {
                    const float wcs = wb + (float)c * invW;
                    v2f Wc = {wcs, wcs};
                    v2f v = y[ch][c] + res2[r][ch][c];
                    v2f a = FMA2(PB0, Wc, FMA2(PC0, v, t0));
                    a = a * FMA2(PB1, Wc, FMA2(PC1, v, t1));
                    a = a * FMA2(PB2, Wc, FMA2(PC2, v, t2));
                    a = a * FMA2(PB3, Wc, FMA2(PC3, v, t3));
                    o[c] = v * (one + a);
                }
                v2f ra = {o[0].x, o[1].x};
                v2f rb2 = {o[0].y, o[1].y};
                float* dp = &dst[((size_t)(b * 3 + ch) * H + gr0) * W + tcol + gx3e];
                __builtin_memcpy(dp, &ra, 8);
                __builtin_memcpy(dp + W, &rb2, 8);
            }
        }
    }
}

extern "C" void kernel_launch(void* const* d_in, const int* in_sizes, int n_in,
                              void* d_out, int out_size, void* d_ws, size_t ws_size,
                              hipStream_t stream) {
    const float* x = (const float*)d_in[0];       // (8,3,512,512)
    const float* thumb = (const float*)d_in[1];   // (8,3,64,64)
    const float* Wm = (const float*)d_in[2];      // (3,360)
    const float* bm = (const float*)d_in[3];      // (360,)
    float* out = (float*)d_out;
    float* feat = (float*)d_ws;                   // (8,360)

    prep_kernel<<<8, 384, 0, stream>>>(thumb, Wm, bm, feat);
    // 1024 big-image blocks + 32 thumb blocks
    conv_att_kernel<<<1056, 256, 0, stream>>>(x, thumb, feat, out);
}

// Round 13
// 114.734 us; speedup vs baseline: 1.0657x; 1.0657x over previous
//
#include <hip/hip_runtime.h>

// ---------------------------------------------------------------------------
// Per-batch dynamic conv stack + polynomial attention (f32).
//   feature (8,360) = mean(thumb,(2,3)) @ Wm + bm
//   conv_stack: residual + [3x conv3x3(SAME,leaky 0.2)] -> [5x conv1x1(leaky)]
//   attention:  out = y * (1 + prod_i(a*h + b*w + c*y + d)) per channel
// Outputs: x_out (8,3,512,512) then thumb_out (8,3,64,64), flat f32.
//
// R20 = R18 per-tile structure (pk-f32, NC=4, col-major CSTR=23 in-place
// LDS, T14 stage0, 4-wave epilogue, 256 thr) + DUAL-TILE pipeline:
//   * R19 lesson: NC=8 broke bank geometry (adjacent lanes 8 cols apart ->
//     step 184 = 24 mod 32, period 4 -> 4 lanes/bank; conflicts 8.7M,
//     2.3x slower). Bank-freedom requires adjacent-lane distance 4 cols.
//     Reverted to NC=4 everywhere.
//   * Remaining exposed latency: stage0 (HBM ~900cy + transpose + barrier)
//     serial at every block head, ~10% of CU time. Fix: 2 tiles/block,
//     2 x 20.2KB buffers. Issue BOTH tiles' loads up front; tile-B's
//     LDS write happens after tile-A's full conv pipeline -> B's HBM
//     latency hides under ~half the block. 1040 blocks (half dispatch).
//   * Pairing: big = adjacent col tiles (same rows); thumb = adjacent row
//     tiles. #pragma unroll tile loop -> all indices compile-time.
//   * VGPR: +24 (tile-B stage regs live across tile-A) -> ~80-100 under
//     the (256,4)=128 cap. LDS 40.4KB -> 3 blocks/CU ceiling (measured
//     residency ~2.4, cap does not bind).
// ---------------------------------------------------------------------------

typedef float v2f __attribute__((ext_vector_type(2)));
#define FMA2(a, b, c) __builtin_elementwise_fma((a), (b), (c))

__device__ __forceinline__ v2f leaky2(v2f v) {
    return __builtin_elementwise_max(v, v * 0.2f);
}

// align-4 LDS pair load/store: compiles to ds_read2_b32 / ds_write2_b32
__device__ __forceinline__ v2f ldpair(const float* p) {
    v2f r; __builtin_memcpy(&r, p, 8); return r;
}
__device__ __forceinline__ void stpair(float* p, v2f v) {
    __builtin_memcpy(p, &v, 8);
}

constexpr int NCOLS = 73;           // cols -4..67 + zero pad col 72
constexpr int CSTR  = 23;           // 22 rows + 1 pad; 4*23=92=28 mod 32 banks
constexpr int CHS   = NCOLS * CSTR; // 1679
constexpr int BUFSZ = 3 * CHS + 4;  // 20.2KB per tile buffer

__global__ __launch_bounds__(384) void prep_kernel(
    const float* __restrict__ thumb, const float* __restrict__ Wm,
    const float* __restrict__ bm, float* __restrict__ feat)
{
    const int b = blockIdx.x;                // 8 blocks
    const int t = threadIdx.x;               // 384
    const int ch = t >> 7;                   // 0..2
    const int l  = t & 127;
    const float4* p = (const float4*)(thumb + (size_t)b * 3 * 4096);
    float s = 0.f;
#pragma unroll
    for (int k = 0; k < 8; ++k) {
        float4 v = p[ch * 1024 + l + k * 128];
        s += v.x + v.y + v.z + v.w;
    }
    __shared__ float red[384];
    red[t] = s;
    __syncthreads();
    for (int off = 64; off > 0; off >>= 1) {
        if (l < off) red[t] += red[t + off];
        __syncthreads();
    }
    if (t < 360) {
        const float sc = 1.f / 4096.f;
        const float m0 = red[0] * sc, m1 = red[128] * sc, m2 = red[256] * sc;
        feat[b * 360 + t] =
            fmaf(m0, Wm[t], fmaf(m1, Wm[360 + t], fmaf(m2, Wm[720 + t], bm[t])));
    }
}

// Packed 3x3 conv over a strip of 2 output rows x NC cols, all 3 och.
// acc[oc][c] = (row r0, row r0+1) packed. rb = buffer row of the first tap
// pair (taps cover buffer rows rb..rb+3). Per (ich, window col) load the
// two disjoint pairs p0=(rb,rb+1), p1=(rb+2,rb+3); middle pm={p0.y,p1.x}.
// gx may be -4 (halo): window col 0 clamps to col 3, feeding only
// discarded outputs.
template<int NC>
__device__ __forceinline__ void conv_rows_pk(
    const float* __restrict__ buf, const float* __restrict__ fw,
    int rb, int gx, v2f acc[3][NC])
{
    const float b0 = fw[81], b1 = fw[82], b2 = fw[83];
#pragma unroll
    for (int c = 0; c < NC; ++c) {
        v2f i0 = {b0, b0}; v2f i1 = {b1, b1}; v2f i2 = {b2, b2};
        acc[0][c] = i0; acc[1][c] = i1; acc[2][c] = i2;
    }
    const int c0 = (gx < 0) ? 3 : gx + 3;
#pragma unroll
    for (int ich = 0; ich < 3; ++ich) {
        const int base = ich * CHS + rb;
        v2f p0[NC + 2], p1[NC + 2], pm[NC + 2];
#pragma unroll
        for (int k = 0; k < NC + 2; ++k) {
            const int cc = (k == 0) ? c0 : (gx + 3 + k);
            p0[k] = ldpair(&buf[base + cc * CSTR]);
            p1[k] = ldpair(&buf[base + cc * CSTR + 2]);
            v2f m = {p0[k].y, p1[k].x};
            pm[k] = m;
        }
#pragma unroll
        for (int dy = 0; dy < 3; ++dy) {
#pragma unroll
            for (int oc = 0; oc < 3; ++oc) {
                const float w0 = fw[oc * 27 + ich * 9 + dy * 3 + 0];
                const float w1 = fw[oc * 27 + ich * 9 + dy * 3 + 1];
                const float w2 = fw[oc * 27 + ich * 9 + dy * 3 + 2];
                v2f W0 = {w0, w0}; v2f W1 = {w1, w1}; v2f W2 = {w2, w2};
#pragma unroll
                for (int c = 0; c < NC; ++c) {
                    const v2f wa = (dy == 0) ? p0[c]     : (dy == 1) ? pm[c]     : p1[c];
                    const v2f wb = (dy == 0) ? p0[c + 1] : (dy == 1) ? pm[c + 1] : p1[c + 1];
                    const v2f wc = (dy == 0) ? p0[c + 2] : (dy == 1) ? pm[c + 2] : p1[c + 2];
                    acc[oc][c] = FMA2(wa, W0, FMA2(wb, W1, FMA2(wc, W2, acc[oc][c])));
                }
            }
        }
    }
}

// Stage registers for one 16x64 tile: 4 main rounds + partial round + halo.
struct StageRegs { float4 stv[4]; float4 st5; float4 hv; };

__device__ __forceinline__ void stage_load(
    const float* __restrict__ sbg, int H, int W, int trow, int tcol, int tid,
    StageRegs& R)
{
#pragma unroll
    for (int i = 0; i < 4; ++i) {
        const int q = tid + 256 * i;           // < 1024
        const int c = q / 352;                 // 352 = 22*16
        const int rem = q - c * 352;
        const int mr = rem >> 4;
        const int k  = rem & 15;
        const int gr = trow + mr - 3;
        const int gc0 = tcol + 4 * k;          // always in [0, W-4]
        float4 v = make_float4(0.f, 0.f, 0.f, 0.f);
        if ((unsigned)gr < (unsigned)H)
            v = *(const float4*)&sbg[(size_t)c * H * W + (size_t)gr * W + gc0];
        R.stv[i] = v;
    }
    R.st5 = make_float4(0.f, 0.f, 0.f, 0.f);
    if (tid < 32) {                            // q = 1024..1055 (c=2)
        const int rem = tid + 1024 - 704;
        const int mr = rem >> 4;
        const int k  = rem & 15;
        const int gr = trow + mr - 3;
        const int gc0 = tcol + 4 * k;
        if ((unsigned)gr < (unsigned)H)
            R.st5 = *(const float4*)&sbg[(size_t)2 * H * W + (size_t)gr * W + gc0];
    }
    R.hv = make_float4(0.f, 0.f, 0.f, 0.f);
    if (tid < 132) {                           // halo cols -4 / +64
        const int hc = tid / 44;               // 44 = 22*2
        const int rem = tid - hc * 44;
        const int hmr = rem >> 1;
        const int hside = rem & 1;
        const int gr = trow + hmr - 3;
        const int gc0 = tcol + (hside ? 64 : -4);
        const bool rok = (unsigned)gr < (unsigned)H;
        const float* gp = sbg + (size_t)hc * H * W + (size_t)(rok ? gr : 0) * W;
        float4 hv = make_float4(0.f, 0.f, 0.f, 0.f);
        if (rok && (unsigned)gc0 <= (unsigned)(W - 4)) {
            hv = *(const float4*)&gp[gc0];
        } else {
            hv.x = (rok && (unsigned)(gc0 + 0) < (unsigned)W) ? gp[gc0 + 0] : 0.f;
            hv.y = (rok && (unsigned)(gc0 + 1) < (unsigned)W) ? gp[gc0 + 1] : 0.f;
            hv.z = (rok && (unsigned)(gc0 + 2) < (unsigned)W) ? gp[gc0 + 2] : 0.f;
            hv.w = (rok && (unsigned)(gc0 + 3) < (unsigned)W) ? gp[gc0 + 3] : 0.f;
        }
        R.hv = hv;
    }
}

__device__ __forceinline__ void stage_write(
    float* __restrict__ buf, int tid, const StageRegs& R)
{
#pragma unroll
    for (int i = 0; i < 4; ++i) {
        const int q = tid + 256 * i;
        const int c = q / 352;
        const int rem = q - c * 352;
        const int mr = rem >> 4;
        const int k  = rem & 15;
        float* bp = &buf[c * CHS + (4 * k + 4) * CSTR + mr];
        bp[0] = R.stv[i].x; bp[CSTR] = R.stv[i].y;
        bp[2 * CSTR] = R.stv[i].z; bp[3 * CSTR] = R.stv[i].w;
    }
    if (tid < 32) {
        const int rem = tid + 1024 - 704;
        const int mr = rem >> 4;
        const int k  = rem & 15;
        float* bp = &buf[2 * CHS + (4 * k + 4) * CSTR + mr];
        bp[0] = R.st5.x; bp[CSTR] = R.st5.y; bp[2 * CSTR] = R.st5.z; bp[3 * CSTR] = R.st5.w;
    }
    if (tid < 132) {
        const int hc = tid / 44;
        const int rem = tid - hc * 44;
        const int hmr = rem >> 1;
        const int hside = rem & 1;
        float* bp = &buf[hc * CHS + (hside ? 68 : 0) * CSTR + hmr];
        bp[0] = R.hv.x; bp[CSTR] = R.hv.y; bp[2 * CSTR] = R.hv.z; bp[3 * CSTR] = R.hv.w;
    }
}

__global__ __launch_bounds__(256, 4) void conv_att_kernel(
    const float* __restrict__ x, const float* __restrict__ thumb,
    const float* __restrict__ feat, float* __restrict__ out)
{
    __shared__ float buf2[2][BUFSZ];           // 40.4KB

    const int id = blockIdx.x;
    const float* src; float* dst; int H, W, b;
    int trow0, tcol0, trow1, tcol1;
    if (id < 1024) {                 // big: 8 b x 32 bands x 4 col-pairs
        b = id >> 7; const int t = id & 127;
        const int band = t >> 2, pr = t & 3;
        H = 512; W = 512;
        trow0 = band * 16; tcol0 = pr * 128;
        trow1 = band * 16; tcol1 = pr * 128 + 64;
        src = x; dst = out;
    } else {                         // thumb: 8 batches x 2 row-tile pairs
        const int i2 = id - 1024;    // 0..15
        b = i2 >> 1; const int p = i2 & 1;
        H = 64; W = 64;
        trow0 = p * 32; tcol0 = 0;
        trow1 = p * 32 + 16; tcol1 = 0;
        src = thumb;
        dst = out + (size_t)8 * 3 * 512 * 512;
    }
    const float* fb = feat + b * 360;    // uniform -> scalar loads
    const int tid = threadIdx.x;
    const float* sbg = src + (size_t)b * 3 * H * W;

    // ---- issue BOTH tiles' global loads; write tile0; tile1 regs wait ----
    StageRegs R0, R1;
    stage_load(sbg, H, W, trow0, tcol0, tid, R0);
    stage_load(sbg, H, W, trow1, tcol1, tid, R1);
    stage_write(&buf2[0][0], tid, R0);
    // zero pad col 72 of both buffers (rows 0..21): only gx=64 edge windows
    // read it, feeding discarded outputs — keep values defined.
    if (tid < 66) {
        const int c = tid / 22, mr = tid - c * 22;
        buf2[0][c * CHS + 72 * CSTR + mr] = 0.f;
        buf2[1][c * CHS + 72 * CSTR + mr] = 0.f;
    }
    __syncthreads();

#pragma unroll
    for (int ti = 0; ti < 2; ++ti) {
        float* buf = &buf2[ti][0];
        const int trow = ti ? trow1 : trow0;
        const int tcol = ti ? tcol1 : tcol0;
        if (ti == 1) {
            // tile-B LDS write: loads issued before tile-A's conv -> hidden
            stage_write(buf, tid, R1);
            __syncthreads();
        }

        // ---- phase 2: conv1 reads + residual stash (reads before writes)
        const bool act1 = tid < 180;
        int s1, gx1;
        if (tid < 160) { s1 = tid >> 4; gx1 = 4 * (tid & 15); }
        else { const int v = tid - 160; s1 = v >> 1; gx1 = (v & 1) ? 64 : -4; }
        v2f acc[3][4];
        if (act1) conv_rows_pk<4>(buf, fb, 2 * s1, gx1, acc);  // rb = r0+2 = 2s

        const int s3e = tid >> 5;            // 0..7
        const int gx3e = 2 * (tid & 31);     // 0..62
        v2f res2[3][2];
#pragma unroll
        for (int ch = 0; ch < 3; ++ch)
#pragma unroll
            for (int c = 0; c < 2; ++c)
                res2[ch][c] = ldpair(&buf[ch * CHS + (gx3e + 4 + c) * CSTR + (2 * s3e + 3)]);
        __syncthreads();

        // conv1 writes: buffer rows 2s1+1, 2s1+2
        if (act1) {
#pragma unroll
            for (int oc = 0; oc < 3; ++oc)
#pragma unroll
                for (int c = 0; c < 4; ++c)
                    stpair(&buf[oc * CHS + (gx1 + 4 + c) * CSTR + (2 * s1 + 1)],
                           leaky2(acc[oc][c]));
        }
        __syncthreads();

        // ---- phase 3: conv2 (in-place): 9 strips x 18 = 162 units
        const bool act2 = tid < 162;
        int s2, gx2;
        if (tid < 144) { s2 = tid >> 4; gx2 = 4 * (tid & 15); }
        else { const int v = tid - 144; s2 = v >> 1; gx2 = (v & 1) ? 64 : -4; }
        if (act2) conv_rows_pk<4>(buf, fb + 84, 2 * s2 + 1, gx2, acc); // rb = r0+2
        __syncthreads();

        if (act2) {
#pragma unroll
            for (int oc = 0; oc < 3; ++oc)
#pragma unroll
                for (int c = 0; c < 4; ++c)
                    stpair(&buf[oc * CHS + (gx2 + 4 + c) * CSTR + (2 * s2 + 2)],
                           leaky2(acc[oc][c]));
        }
        __syncthreads();

        // ---- phase 4: conv3 (2-col units, ALL 256 threads) + 1x1 chain
        //      + residual + attention + 8B stores ----
        {
            v2f y[3][2];
            {
                v2f acc3[3][2];
                conv_rows_pk<2>(buf, fb + 168, 2 * s3e + 2, gx3e, acc3); // rb = r0+2
#pragma unroll
                for (int oc = 0; oc < 3; ++oc)
#pragma unroll
                    for (int c = 0; c < 2; ++c) y[oc][c] = leaky2(acc3[oc][c]);
            }

            // 5x conv1x1 chain, packed over the row pair
#pragma unroll
            for (int lay = 0; lay < 5; ++lay) {
                const float* fw = fb + 252 + lay * 12;
                v2f W0 = {fw[0], fw[0]}; v2f W1 = {fw[1], fw[1]}; v2f W2 = {fw[2], fw[2]};
                v2f W3 = {fw[3], fw[3]}; v2f W4 = {fw[4], fw[4]}; v2f W5 = {fw[5], fw[5]};
                v2f W6 = {fw[6], fw[6]}; v2f W7 = {fw[7], fw[7]}; v2f W8 = {fw[8], fw[8]};
                v2f C0 = {fw[9], fw[9]}; v2f C1 = {fw[10], fw[10]}; v2f C2 = {fw[11], fw[11]};
                v2f z0[2], z1[2], z2[2];
#pragma unroll
                for (int c = 0; c < 2; ++c) {
                    z0[c] = FMA2(y[0][c], W0, FMA2(y[1][c], W1, FMA2(y[2][c], W2, C0)));
                    z1[c] = FMA2(y[0][c], W3, FMA2(y[1][c], W4, FMA2(y[2][c], W5, C1)));
                    z2[c] = FMA2(y[0][c], W6, FMA2(y[1][c], W7, FMA2(y[2][c], W8, C2)));
                }
#pragma unroll
                for (int c = 0; c < 2; ++c) {
                    y[0][c] = leaky2(z0[c]);
                    y[1][c] = leaky2(z1[c]);
                    y[2][c] = leaky2(z2[c]);
                }
            }

            // residual + attention + store (2 rows x 2 cols x 3 ch)
            const float invH = 1.f / (float)H;
            const float invW = 1.f / (float)W;
            const int gr0 = trow + 2 * s3e;
            v2f h2 = {(float)gr0 * invH, (float)(gr0 + 1) * invH};
            const float wb = (float)(tcol + gx3e) * invW;
            const v2f one = {1.f, 1.f};
#pragma unroll
            for (int ch = 0; ch < 3; ++ch) {
                const float* fp = fb + 312 + ch * 16;
                v2f PA0 = {fp[0], fp[0]},  PB0 = {fp[1], fp[1]},  PC0 = {fp[2], fp[2]},  PD0 = {fp[3], fp[3]};
                v2f PA1 = {fp[4], fp[4]},  PB1 = {fp[5], fp[5]},  PC1 = {fp[6], fp[6]},  PD1 = {fp[7], fp[7]};
                v2f PA2 = {fp[8], fp[8]},  PB2 = {fp[9], fp[9]},  PC2 = {fp[10], fp[10]}, PD2 = {fp[11], fp[11]};
                v2f PA3 = {fp[12], fp[12]}, PB3 = {fp[13], fp[13]}, PC3 = {fp[14], fp[14]}, PD3 = {fp[15], fp[15]};
                v2f t0 = FMA2(PA0, h2, PD0);
                v2f t1 = FMA2(PA1, h2, PD1);
                v2f t2 = FMA2(PA2, h2, PD2);
                v2f t3 = FMA2(PA3, h2, PD3);
                v2f o[2];
#pragma unroll
                for (int c = 0; c < 2; ++c) {
                    const float wcs = wb + (float)c * invW;
                    v2f Wc = {wcs, wcs};
                    v2f v = y[ch][c] + res2[ch][c];
                    v2f a = FMA2(PB0, Wc, FMA2(PC0, v, t0));
                    a = a * FMA2(PB1, Wc, FMA2(PC1, v, t1));
                    a = a * FMA2(PB2, Wc, FMA2(PC2, v, t2));
                    a = a * FMA2(PB3, Wc, FMA2(PC3, v, t3));
                    o[c] = v * (one + a);
                }
                v2f ra = {o[0].x, o[1].x};
                v2f rb2 = {o[0].y, o[1].y};
                float* dp = &dst[((size_t)(b * 3 + ch) * H + gr0) * W + tcol + gx3e];
                __builtin_memcpy(dp, &ra, 8);
                __builtin_memcpy(dp + W, &rb2, 8);
            }
        }
    }
}

extern "C" void kernel_launch(void* const* d_in, const int* in_sizes, int n_in,
                              void* d_out, int out_size, void* d_ws, size_t ws_size,
                              hipStream_t stream) {
    const float* x = (const float*)d_in[0];       // (8,3,512,512)
    const float* thumb = (const float*)d_in[1];   // (8,3,64,64)
    const float* Wm = (const float*)d_in[2];      // (3,360)
    const float* bm = (const float*)d_in[3];      // (360,)
    float* out = (float*)d_out;
    float* feat = (float*)d_ws;                   // (8,360)

    prep_kernel<<<8, 384, 0, stream>>>(thumb, Wm, bm, feat);
    // 1024 big-image dual-tile blocks + 16 thumb dual-tile blocks
    conv_att_kernel<<<1040, 256, 0, stream>>>(x, thumb, feat, out);
}

// Round 14
// 105.937 us; speedup vs baseline: 1.1542x; 1.0830x over previous
//
#include <hip/hip_runtime.h>

// ---------------------------------------------------------------------------
// Per-batch dynamic conv stack + polynomial attention (f32).
//   feature (8,360) = mean(thumb,(2,3)) @ Wm + bm
//   conv_stack: residual + [3x conv3x3(SAME,leaky 0.2)] -> [5x conv1x1(leaky)]
//   attention:  out = y * (1 + prod_i(a*h + b*w + c*y + d)) per channel
// Outputs: x_out (8,3,512,512) then thumb_out (8,3,64,64), flat f32.
//
// R21 = R16 verbatim (best verified: harness 106.47us, conv_att ~38us).
// Revert from R20 (dual-tile, -18%: LDS 40.4KB cut occupancy 30->24%,
// double-staged halo raised FETCH, tile-B regs throttled the scheduler).
//
// Session ledger: instruction-count cuts (pk-f32 R12, col-major pair loads
// R13, dy-overlap + 4-wave epilogue R16) took 49.6 -> 38us. Bank-layout
// (R8/R11/R14), barriers (R15), occupancy both ways (R17/R18), wide-unit
// ILP (R19), cross-tile pipeline (R20) all null or negative — falsifiers
// fired on every remaining lever. ~38us is this structure's practical
// floor: VALU ~36k cyc/CU + LDS ~36k cyc/CU partially overlapped at the
// scheduler-pinned ~2.4 waves/SIMD.
//
// R16 structure: pk-f32 math (v_pk_fma via ext_vector), col-major LDS
// [ch][col][row] CSTR=23 (2 lanes/bank engineered), ping-pong A->B->A
// (3 barriers), T14 stage0 (issue all loads, then write), dy-overlap
// conv loads (36 pair-loads/unit), conv1/conv2 NC=4 phase-aligned+halo
// lanes, conv3+epilogue NC=2 on all 4 waves, residual in regs, 8B
// row-pair stores (128B-contiguous per 16 lanes).
// ---------------------------------------------------------------------------

typedef float v2f __attribute__((ext_vector_type(2)));
#define FMA2(a, b, c) __builtin_elementwise_fma((a), (b), (c))

__device__ __forceinline__ v2f leaky2(v2f v) {
    return __builtin_elementwise_max(v, v * 0.2f);
}

// align-4 LDS pair load/store: compiles to ds_read2_b32 / ds_write2_b32
__device__ __forceinline__ v2f ldpair(const float* p) {
    v2f r; __builtin_memcpy(&r, p, 8); return r;
}
__device__ __forceinline__ void stpair(float* p, v2f v) {
    __builtin_memcpy(p, &v, 8);
}

constexpr int NCOLS = 73;            // cols -4..67 + zero pad col 72
constexpr int CSTRA = 23;            // A: input/conv2-out, 22 rows + pad
constexpr int CHSA  = NCOLS * CSTRA; // 1679
constexpr int ASZ   = 3 * CHSA + 4;  // 20.2KB
constexpr int CSTRB = 21;            // B: conv1-out, 20 rows + pad
constexpr int CHSB  = NCOLS * CSTRB; // 1533
constexpr int BSZ   = 3 * CHSB + 4;  // 18.4KB

__global__ __launch_bounds__(384) void prep_kernel(
    const float* __restrict__ thumb, const float* __restrict__ Wm,
    const float* __restrict__ bm, float* __restrict__ feat)
{
    const int b = blockIdx.x;                // 8 blocks
    const int t = threadIdx.x;               // 384
    const int ch = t >> 7;                   // 0..2
    const int l  = t & 127;
    const float4* p = (const float4*)(thumb + (size_t)b * 3 * 4096);
    float s = 0.f;
#pragma unroll
    for (int k = 0; k < 8; ++k) {
        float4 v = p[ch * 1024 + l + k * 128];
        s += v.x + v.y + v.z + v.w;
    }
    __shared__ float red[384];
    red[t] = s;
    __syncthreads();
    for (int off = 64; off > 0; off >>= 1) {
        if (l < off) red[t] += red[t + off];
        __syncthreads();
    }
    if (t < 360) {
        const float sc = 1.f / 4096.f;
        const float m0 = red[0] * sc, m1 = red[128] * sc, m2 = red[256] * sc;
        feat[b * 360 + t] =
            fmaf(m0, Wm[t], fmaf(m1, Wm[360 + t], fmaf(m2, Wm[720 + t], bm[t])));
    }
}

// Packed 3x3 conv over a strip of 2 output rows x NC cols, all 3 och.
// acc[oc][c] = (row r0, row r0+1) packed. rb = buffer row of the first tap
// pair (taps cover buffer rows rb..rb+3). Per (ich, window col) load the
// two disjoint pairs p0=(rb,rb+1), p1=(rb+2,rb+3); middle pm={p0.y,p1.x}.
// gx may be -4 (halo): window col 0 clamps to col 3, feeding only
// discarded outputs.
template<int CHS_, int CSTR_, int NC>
__device__ __forceinline__ void conv_rows_pk(
    const float* __restrict__ buf, const float* __restrict__ fw,
    int rb, int gx, v2f acc[3][NC])
{
    const float b0 = fw[81], b1 = fw[82], b2 = fw[83];
#pragma unroll
    for (int c = 0; c < NC; ++c) {
        v2f i0 = {b0, b0}; v2f i1 = {b1, b1}; v2f i2 = {b2, b2};
        acc[0][c] = i0; acc[1][c] = i1; acc[2][c] = i2;
    }
    const int c0 = (gx < 0) ? 3 : gx + 3;
#pragma unroll
    for (int ich = 0; ich < 3; ++ich) {
        const int base = ich * CHS_ + rb;
        v2f p0[NC + 2], p1[NC + 2], pm[NC + 2];
#pragma unroll
        for (int k = 0; k < NC + 2; ++k) {
            const int cc = (k == 0) ? c0 : (gx + 3 + k);
            p0[k] = ldpair(&buf[base + cc * CSTR_]);
            p1[k] = ldpair(&buf[base + cc * CSTR_ + 2]);
            v2f m = {p0[k].y, p1[k].x};
            pm[k] = m;
        }
#pragma unroll
        for (int dy = 0; dy < 3; ++dy) {
#pragma unroll
            for (int oc = 0; oc < 3; ++oc) {
                const float w0 = fw[oc * 27 + ich * 9 + dy * 3 + 0];
                const float w1 = fw[oc * 27 + ich * 9 + dy * 3 + 1];
                const float w2 = fw[oc * 27 + ich * 9 + dy * 3 + 2];
                v2f W0 = {w0, w0}; v2f W1 = {w1, w1}; v2f W2 = {w2, w2};
#pragma unroll
                for (int c = 0; c < NC; ++c) {
                    const v2f wa = (dy == 0) ? p0[c]     : (dy == 1) ? pm[c]     : p1[c];
                    const v2f wb = (dy == 0) ? p0[c + 1] : (dy == 1) ? pm[c + 1] : p1[c + 1];
                    const v2f wc = (dy == 0) ? p0[c + 2] : (dy == 1) ? pm[c + 2] : p1[c + 2];
                    acc[oc][c] = FMA2(wa, W0, FMA2(wb, W1, FMA2(wc, W2, acc[oc][c])));
                }
            }
        }
    }
}

__global__ __launch_bounds__(256, 4) void conv_att_kernel(
    const float* __restrict__ x, const float* __restrict__ thumb,
    const float* __restrict__ feat, float* __restrict__ out)
{
    __shared__ float bufA[ASZ];
    __shared__ float bufB[BSZ];

    int id = blockIdx.x;
    const float* src; float* dst; int H, W, b, trow, tcol;
    if (id < 2048) {                 // big: 8 batches x (32 row x 8 col) tiles
        b = id >> 8; const int t = id & 255;
        H = 512; W = 512; trow = (t >> 3) * 16; tcol = (t & 7) * 64;
        src = x; dst = out;
    } else {                         // thumb: 8 batches x 4 row tiles
        const int i2 = id - 2048;
        b = i2 >> 2; trow = (i2 & 3) * 16; tcol = 0;
        H = 64; W = 64; src = thumb;
        dst = out + (size_t)8 * 3 * 512 * 512;
    }
    const float* fb = feat + b * 360;    // uniform -> scalar loads
    const int tid = threadIdx.x;

    // ---- stage0: issue ALL global loads first (regs), then write LDS ----
    const float* sbg = src + (size_t)b * 3 * H * W;
    float4 stv[4];
#pragma unroll
    for (int i = 0; i < 4; ++i) {
        const int q = tid + 256 * i;           // < 1024
        const int c = q / 352;                 // 352 = 22*16
        const int rem = q - c * 352;
        const int mr = rem >> 4;
        const int k  = rem & 15;
        const int gr = trow + mr - 3;
        const int gc0 = tcol + 4 * k;          // always in [0, W-4]
        float4 v = make_float4(0.f, 0.f, 0.f, 0.f);
        if ((unsigned)gr < (unsigned)H)
            v = *(const float4*)&sbg[(size_t)c * H * W + (size_t)gr * W + gc0];
        stv[i] = v;
    }
    const bool has5 = tid < 32;                // q = 1024..1055 (c=2)
    float4 st5 = make_float4(0.f, 0.f, 0.f, 0.f);
    if (has5) {
        const int rem = tid + 1024 - 704;      // c = 2
        const int mr = rem >> 4;
        const int k  = rem & 15;
        const int gr = trow + mr - 3;
        const int gc0 = tcol + 4 * k;
        if ((unsigned)gr < (unsigned)H)
            st5 = *(const float4*)&sbg[(size_t)2 * H * W + (size_t)gr * W + gc0];
    }
    // halo: cols 0..3 (img tcol-4) and 68..71 (img tcol+64), 132 units
    const bool hasH = tid < 132;
    float4 hv = make_float4(0.f, 0.f, 0.f, 0.f);
    int hc = 0, hmr = 0, hside = 0;
    if (hasH) {
        hc = tid / 44;                         // 44 = 22*2
        const int rem = tid - hc * 44;
        hmr = rem >> 1;
        hside = rem & 1;
        const int gr = trow + hmr - 3;
        const int gc0 = tcol + (hside ? 64 : -4);
        const bool rok = (unsigned)gr < (unsigned)H;
        const float* gp = sbg + (size_t)hc * H * W + (size_t)(rok ? gr : 0) * W;
        if (rok && (unsigned)gc0 <= (unsigned)(W - 4)) {
            hv = *(const float4*)&gp[gc0];
        } else {
            hv.x = (rok && (unsigned)(gc0 + 0) < (unsigned)W) ? gp[gc0 + 0] : 0.f;
            hv.y = (rok && (unsigned)(gc0 + 1) < (unsigned)W) ? gp[gc0 + 1] : 0.f;
            hv.z = (rok && (unsigned)(gc0 + 2) < (unsigned)W) ? gp[gc0 + 2] : 0.f;
            hv.w = (rok && (unsigned)(gc0 + 3) < (unsigned)W) ? gp[gc0 + 3] : 0.f;
        }
    }
    // writes (transpose into col-major A)
#pragma unroll
    for (int i = 0; i < 4; ++i) {
        const int q = tid + 256 * i;
        const int c = q / 352;
        const int rem = q - c * 352;
        const int mr = rem >> 4;
        const int k  = rem & 15;
        float* bp = &bufA[c * CHSA + (4 * k + 4) * CSTRA + mr];
        bp[0] = stv[i].x; bp[CSTRA] = stv[i].y;
        bp[2 * CSTRA] = stv[i].z; bp[3 * CSTRA] = stv[i].w;
    }
    if (has5) {
        const int rem = tid + 1024 - 704;
        const int mr = rem >> 4;
        const int k  = rem & 15;
        float* bp = &bufA[2 * CHSA + (4 * k + 4) * CSTRA + mr];
        bp[0] = st5.x; bp[CSTRA] = st5.y; bp[2 * CSTRA] = st5.z; bp[3 * CSTRA] = st5.w;
    }
    if (hasH) {
        float* bp = &bufA[hc * CHSA + (hside ? 68 : 0) * CSTRA + hmr];
        bp[0] = hv.x; bp[CSTRA] = hv.y; bp[2 * CSTRA] = hv.z; bp[3 * CSTRA] = hv.w;
    }
    // zero pads: A col 72 (rows 0..21), B col 72 (rows 0..19)
    if (tid < 66) {
        const int c = tid / 22, mr = tid - c * 22;
        bufA[c * CHSA + 72 * CSTRA + mr] = 0.f;
    } else if (tid < 126) {
        const int t2 = tid - 66;
        const int c = t2 / 20, r = t2 - c * 20;
        bufB[c * CHSB + 72 * CSTRB + r] = 0.f;
    }
    __syncthreads();

    // ---- phase 2: residual stash (reads A) + conv1 (A -> B) ----
    // epilogue mapping (all 256 threads): strip s3e rows (2s3e, 2s3e+1),
    // cols gx3e, gx3e+1
    const int s3e = tid >> 5;            // 0..7
    const int gx3e = 2 * (tid & 31);     // 0..62
    v2f res2[3][2];
#pragma unroll
    for (int ch = 0; ch < 3; ++ch)
#pragma unroll
        for (int c = 0; c < 2; ++c)
            res2[ch][c] = ldpair(&bufA[ch * CHSA + (gx3e + 4 + c) * CSTRA + (2 * s3e + 3)]);
    // conv1: 10 strips (r0 = 2s-2) x 18 quads = 180 units
    {
        const bool act1 = tid < 180;
        int s1, gx1;
        if (tid < 160) { s1 = tid >> 4; gx1 = 4 * (tid & 15); }
        else { const int v = tid - 160; s1 = v >> 1; gx1 = (v & 1) ? 64 : -4; }
        if (act1) {
            v2f acc[3][4];
            // rb = 2*s1 (A rows = img+3); B write row = 2*s1 (B rows = img+2)
            conv_rows_pk<CHSA, CSTRA, 4>(bufA, fb, 2 * s1, gx1, acc);
#pragma unroll
            for (int oc = 0; oc < 3; ++oc)
#pragma unroll
                for (int c = 0; c < 4; ++c)
                    stpair(&bufB[oc * CHSB + (gx1 + 4 + c) * CSTRB + 2 * s1],
                           leaky2(acc[oc][c]));
        }
    }
    __syncthreads();

    // ---- phase 3: conv2 (B -> A; input rows dead, residual in regs) ----
    {
        const bool act2 = tid < 162;
        int s2, gx2;
        if (tid < 144) { s2 = tid >> 4; gx2 = 4 * (tid & 15); }
        else { const int v = tid - 144; s2 = v >> 1; gx2 = (v & 1) ? 64 : -4; }
        if (act2) {
            v2f acc[3][4];
            // rb = 2*s2 (B rows = img+2); A write row = 2*s2+2 (A rows = img+3)
            conv_rows_pk<CHSB, CSTRB, 4>(bufB, fb + 84, 2 * s2, gx2, acc);
#pragma unroll
            for (int oc = 0; oc < 3; ++oc)
#pragma unroll
                for (int c = 0; c < 4; ++c)
                    stpair(&bufA[oc * CHSA + (gx2 + 4 + c) * CSTRA + 2 * s2 + 2],
                           leaky2(acc[oc][c]));
        }
    }
    __syncthreads();

    // ---- phase 4: conv3 (2-col units, ALL 256 threads) + 1x1 chain
    //      + residual + attention + 8B stores ----
    {
        v2f y[3][2];
        {
            v2f acc3[3][2];
            // rb = 2*s3e+2 (A rows = img+3, first tap img row 2s3e-1)
            conv_rows_pk<CHSA, CSTRA, 2>(bufA, fb + 168, 2 * s3e + 2, gx3e, acc3);
#pragma unroll
            for (int oc = 0; oc < 3; ++oc)
#pragma unroll
                for (int c = 0; c < 2; ++c) y[oc][c] = leaky2(acc3[oc][c]);
        }

        // 5x conv1x1 chain, packed over the row pair
#pragma unroll
        for (int lay = 0; lay < 5; ++lay) {
            const float* fw = fb + 252 + lay * 12;
            v2f W0 = {fw[0], fw[0]}; v2f W1 = {fw[1], fw[1]}; v2f W2 = {fw[2], fw[2]};
            v2f W3 = {fw[3], fw[3]}; v2f W4 = {fw[4], fw[4]}; v2f W5 = {fw[5], fw[5]};
            v2f W6 = {fw[6], fw[6]}; v2f W7 = {fw[7], fw[7]}; v2f W8 = {fw[8], fw[8]};
            v2f C0 = {fw[9], fw[9]}; v2f C1 = {fw[10], fw[10]}; v2f C2 = {fw[11], fw[11]};
            v2f z0[2], z1[2], z2[2];
#pragma unroll
            for (int c = 0; c < 2; ++c) {
                z0[c] = FMA2(y[0][c], W0, FMA2(y[1][c], W1, FMA2(y[2][c], W2, C0)));
                z1[c] = FMA2(y[0][c], W3, FMA2(y[1][c], W4, FMA2(y[2][c], W5, C1)));
                z2[c] = FMA2(y[0][c], W6, FMA2(y[1][c], W7, FMA2(y[2][c], W8, C2)));
            }
#pragma unroll
            for (int c = 0; c < 2; ++c) {
                y[0][c] = leaky2(z0[c]);
                y[1][c] = leaky2(z1[c]);
                y[2][c] = leaky2(z2[c]);
            }
        }

        // residual + attention + store (2 rows x 2 cols x 3 ch)
        const float invH = 1.f / (float)H;
        const float invW = 1.f / (float)W;
        const int gr0 = trow + 2 * s3e;
        v2f h2 = {(float)gr0 * invH, (float)(gr0 + 1) * invH};
        const float wb = (float)(tcol + gx3e) * invW;
        const v2f one = {1.f, 1.f};
#pragma unroll
        for (int ch = 0; ch < 3; ++ch) {
            const float* fp = fb + 312 + ch * 16;
            v2f PA0 = {fp[0], fp[0]},  PB0 = {fp[1], fp[1]},  PC0 = {fp[2], fp[2]},  PD0 = {fp[3], fp[3]};
            v2f PA1 = {fp[4], fp[4]},  PB1 = {fp[5], fp[5]},  PC1 = {fp[6], fp[6]},  PD1 = {fp[7], fp[7]};
            v2f PA2 = {fp[8], fp[8]},  PB2 = {fp[9], fp[9]},  PC2 = {fp[10], fp[10]}, PD2 = {fp[11], fp[11]};
            v2f PA3 = {fp[12], fp[12]}, PB3 = {fp[13], fp[13]}, PC3 = {fp[14], fp[14]}, PD3 = {fp[15], fp[15]};
            v2f t0 = FMA2(PA0, h2, PD0);
            v2f t1 = FMA2(PA1, h2, PD1);
            v2f t2 = FMA2(PA2, h2, PD2);
            v2f t3 = FMA2(PA3, h2, PD3);
            v2f o[2];
#pragma unroll
            for (int c = 0; c < 2; ++c) {
                const float wcs = wb + (float)c * invW;
                v2f Wc = {wcs, wcs};
                v2f v = y[ch][c] + res2[ch][c];
                v2f a = FMA2(PB0, Wc, FMA2(PC0, v, t0));
                a = a * FMA2(PB1, Wc, FMA2(PC1, v, t1));
                a = a * FMA2(PB2, Wc, FMA2(PC2, v, t2));
                a = a * FMA2(PB3, Wc, FMA2(PC3, v, t3));
                o[c] = v * (one + a);
            }
            v2f ra = {o[0].x, o[1].x};
            v2f rb2 = {o[0].y, o[1].y};
            float* dp = &dst[((size_t)(b * 3 + ch) * H + gr0) * W + tcol + gx3e];
            __builtin_memcpy(dp, &ra, 8);
            __builtin_memcpy(dp + W, &rb2, 8);
        }
    }
}

extern "C" void kernel_launch(void* const* d_in, const int* in_sizes, int n_in,
                              void* d_out, int out_size, void* d_ws, size_t ws_size,
                              hipStream_t stream) {
    const float* x = (const float*)d_in[0];       // (8,3,512,512)
    const float* thumb = (const float*)d_in[1];   // (8,3,64,64)
    const float* Wm = (const float*)d_in[2];      // (3,360)
    const float* bm = (const float*)d_in[3];      // (360,)
    float* out = (float*)d_out;
    float* feat = (float*)d_ws;                   // (8,360)

    prep_kernel<<<8, 384, 0, stream>>>(thumb, Wm, bm, feat);
    // 2048 big-image blocks + 32 thumb blocks
    conv_att_kernel<<<2080, 256, 0, stream>>>(x, thumb, feat, out);
}